// Round 12
// baseline (299.143 us; speedup 1.0000x reference)
//
#include <hip/hip_runtime.h>

// Capsule dynamic routing via MFMA, fused, u_hat never materialized.
//   x: [B=64, In=2048, K=16] fp32;  W: [N=32, In=2048, D=32, K=16] fp32
//   out v: [B=64, N=32, D=32] fp32
// Identities: b_t = u_hat . Vsum (logits linear in agreements); c_1 = 1/32.
// Per (n,i): u[d,b] = W[n,i] (32x16) @ x^T (16x64) via 2 b-tiles of
// mfma_f32_32x32x16_bf16.
// Structure (round-10 skeleton, best measured = 176.6 us):
//   kT   : x -> xh/xl bf16 [In][B][K]
//   kS1c : iter-1 s (uniform c=1/32) from fp32 W (bf16x3), fused W->Wb convert
//          chunk=8 (round 11: TLP, 32 waves/CU; was 16 @ 30% occupancy)
//   kA   : logits (single MFMA, Wb*xh), chunk=8
//   kSM  : softmax over n (in-place, bf16 ct)
//   kS   : weighted sum (Wb, x hi+lo), chunk=16 (already at byte-ideal)
//   kR1h/kR2 : wide reduction (chunk-count param) + squash
// NOTE (round-3): tiny-grid reduction kernels are latency disasters.
// NOTE (rounds 5/8/9): ALL fusion attempts lost 30-160 us. Streaming wins;
// kernels are latency-bound -> wave count (TLP) is the lever that works.
// NOTE (round-11): bench infra failure (UnresponsiveContainer); resubmitted.

#define INP 2048
#define BB 64
#define KK 16
#define NN 32
#define DD 32
#define ICH 16
#define NCHUNK (INP / ICH)  // 128 (kS)
#define S1CH 8
#define S1NCH (INP / S1CH)  // 256 (kS1c)
#define ACH 8
#define ANCH (INP / ACH)    // 256 (kA)

typedef __attribute__((ext_vector_type(8))) short short8;
typedef __attribute__((ext_vector_type(16))) float f32x16;

__device__ __forceinline__ short bf_trunc(float f) {
  return (short)(__builtin_bit_cast(unsigned, f) >> 16);
}
__device__ __forceinline__ unsigned short bf_round(float f) {
  unsigned u = __builtin_bit_cast(unsigned, f);
  return (unsigned short)((u + 0x8000u) >> 16);
}
__device__ __forceinline__ float bf2f(unsigned short u) {
  return __builtin_bit_cast(float, (unsigned)u << 16);
}

__device__ __forceinline__ void split8(float4 w0, float4 w1, short8& h, short8& l) {
  float f[8] = {w0.x, w0.y, w0.z, w0.w, w1.x, w1.y, w1.z, w1.w};
#pragma unroll
  for (int j = 0; j < 8; ++j) {
    unsigned u = __builtin_bit_cast(unsigned, f[j]);
    h[j] = (short)(u >> 16);
    float hf = __builtin_bit_cast(float, u & 0xFFFF0000u);
    l[j] = bf_trunc(f[j] - hf);
  }
}

// round-to-nearest bf16 of 8 fp32 (for the stored Wb)
__device__ __forceinline__ short8 round8(float4 w0, float4 w1) {
  float f[8] = {w0.x, w0.y, w0.z, w0.w, w1.x, w1.y, w1.z, w1.w};
  short8 r;
#pragma unroll
  for (int j = 0; j < 8; ++j) r[j] = (short)bf_round(f[j]);
  return r;
}

// ------------------------------------------------------------------ kT
// transpose x [B][In][K] fp32 -> xt_hi/xt_lo [In][B][K] bf16
__global__ __launch_bounds__(256) void kT(const float* __restrict__ x,
                                          short* __restrict__ xh,
                                          short* __restrict__ xl) {
  const int t = blockIdx.x * 256 + threadIdx.x; // In*B = 131072
  const int i = t >> 6, b = t & 63;
  const float4* xs = (const float4*)(x + ((size_t)b * INP + i) * KK);
  short8* dh = (short8*)(xh + ((size_t)i * BB + b) * KK);
  short8* dl = (short8*)(xl + ((size_t)i * BB + b) * KK);
#pragma unroll
  for (int h = 0; h < 2; ++h) {
    short8 hh, ll;
    split8(xs[h * 2], xs[h * 2 + 1], hh, ll);
    dh[h] = hh;
    dl[h] = ll;
  }
}

// ------------------------------------------------------------------ kS1c
// iteration 1 (c uniform = 1/32) + W->bf16 conversion. wave = (n, i-chunk of 8).
// bf16x3 MFMA from fp32 W; writes Wb and bf16 spart (256 chunks).
__global__ __launch_bounds__(256) void kS1c(const float* __restrict__ W,
                                            const short* __restrict__ xh,
                                            const short* __restrict__ xl,
                                            short* __restrict__ Wb,
                                            unsigned short* __restrict__ spart) {
  const int wv = threadIdx.x >> 6;
  const int lane = threadIdx.x & 63;
  const int bl = lane & 31;
  const int hi = lane >> 5;
  const int w = blockIdx.x * 4 + wv;
  const int n = w >> 8;           // / S1NCH
  const int ch = w & (S1NCH - 1);

  f32x16 s0 = {};
  f32x16 s1 = {};

  const size_t fragoff = (((size_t)n * INP + (size_t)ch * S1CH) * DD + bl) * KK + hi * 8;
  const float* Wp = W + fragoff;
  short* Wbp = Wb + fragoff;
  const short* xhp = xh + (size_t)ch * S1CH * BB * KK + hi * 8;
  const short* xlp = xl + (size_t)ch * S1CH * BB * KK + hi * 8;

#pragma unroll 2
  for (int ii = 0; ii < S1CH; ++ii) {
    float4 w0 = *(const float4*)(Wp + (size_t)ii * (DD * KK));
    float4 w1 = *(const float4*)(Wp + (size_t)ii * (DD * KK) + 4);
    short8 whi, wlo;
    split8(w0, w1, whi, wlo);
    *(short8*)(Wbp + (size_t)ii * (DD * KK)) = round8(w0, w1); // store Wb
    const short8 x0h = *(const short8*)(xhp + ii * (BB * KK) + bl * KK);
    const short8 x0l = *(const short8*)(xlp + ii * (BB * KK) + bl * KK);
    const short8 x1h = *(const short8*)(xhp + ii * (BB * KK) + (bl + 32) * KK);
    const short8 x1l = *(const short8*)(xlp + ii * (BB * KK) + (bl + 32) * KK);
    s0 = __builtin_amdgcn_mfma_f32_32x32x16_bf16(whi, x0h, s0, 0, 0, 0);
    s0 = __builtin_amdgcn_mfma_f32_32x32x16_bf16(whi, x0l, s0, 0, 0, 0);
    s0 = __builtin_amdgcn_mfma_f32_32x32x16_bf16(wlo, x0h, s0, 0, 0, 0);
    s1 = __builtin_amdgcn_mfma_f32_32x32x16_bf16(whi, x1h, s1, 0, 0, 0);
    s1 = __builtin_amdgcn_mfma_f32_32x32x16_bf16(whi, x1l, s1, 0, 0, 0);
    s1 = __builtin_amdgcn_mfma_f32_32x32x16_bf16(wlo, x1h, s1, 0, 0, 0);
  }

  const size_t off = ((size_t)ch * NN + n) * (DD * BB);
#pragma unroll
  for (int r = 0; r < 16; ++r) {
    const int d = (r & 3) + 8 * (r >> 2) + 4 * hi;
    spart[off + d * BB + bl] = bf_round(0.03125f * s0[r]);
    spart[off + d * BB + bl + 32] = bf_round(0.03125f * s1[r]);
  }
}

// ------------------------------------------------------------------ kA
// wave = (n, i-chunk of 8). a[b,n,i] = sum_d u[d,b]*vsum[b,n,d] -> ct bf16.
// single-MFMA u (x hi only): logit error is softmax-damped + i-averaged.
__global__ __launch_bounds__(256) void kA(const short* __restrict__ Wb,
                                          const short* __restrict__ xh,
                                          const float* __restrict__ vsum,
                                          unsigned short* __restrict__ ct) {
  const int wv = threadIdx.x >> 6;
  const int lane = threadIdx.x & 63;
  const int bl = lane & 31;
  const int hi = lane >> 5;
  const int w = blockIdx.x * 4 + wv;
  const int n = w >> 8;           // / ANCH
  const int ch = w & (ANCH - 1);

  float vr0[16], vr1[16];
#pragma unroll
  for (int r = 0; r < 16; ++r) {
    const int d = (r & 3) + 8 * (r >> 2) + 4 * hi;
    vr0[r] = vsum[((size_t)n * DD + d) * BB + bl];
    vr1[r] = vsum[((size_t)n * DD + d) * BB + bl + 32];
  }

  const short* Wp = Wb + (((size_t)n * INP + (size_t)ch * ACH) * DD + bl) * KK + hi * 8;
  const short* xhp = xh + (size_t)ch * ACH * BB * KK + hi * 8;

#pragma unroll 2
  for (int ii = 0; ii < ACH; ++ii) {
    const short8 whi = *(const short8*)(Wp + (size_t)ii * (DD * KK));
    const short8 x0h = *(const short8*)(xhp + ii * (BB * KK) + bl * KK);
    const short8 x1h = *(const short8*)(xhp + ii * (BB * KK) + (bl + 32) * KK);

    f32x16 u0 = {};
    u0 = __builtin_amdgcn_mfma_f32_32x32x16_bf16(whi, x0h, u0, 0, 0, 0);
    f32x16 u1 = {};
    u1 = __builtin_amdgcn_mfma_f32_32x32x16_bf16(whi, x1h, u1, 0, 0, 0);

    float p0 = 0.f, p1 = 0.f;
#pragma unroll
    for (int r = 0; r < 16; ++r) {
      p0 += u0[r] * vr0[r];
      p1 += u1[r] * vr1[r];
    }
    p0 += __shfl_xor(p0, 32, 64);
    p1 += __shfl_xor(p1, 32, 64);
    const int i = ch * ACH + ii;
    ct[((size_t)i * NN + n) * BB + lane] = bf_round((lane < 32) ? p0 : p1);
  }
}

// ------------------------------------------------------------------ kSM
// in-place softmax over n for each (i, b); wave per i, lane = b. bf16 ct.
__global__ __launch_bounds__(256) void kSM(unsigned short* __restrict__ ct) {
  const int wv = threadIdx.x >> 6;
  const int lane = threadIdx.x & 63;
  const int i = blockIdx.x * 4 + wv;
  unsigned short* p = ct + (size_t)i * NN * BB + lane;
  float a[NN];
  float m = -1e30f;
#pragma unroll
  for (int n = 0; n < NN; ++n) {
    a[n] = bf2f(p[n * BB]);
    m = fmaxf(m, a[n]);
  }
  float s = 0.f;
#pragma unroll
  for (int n = 0; n < NN; ++n) {
    a[n] = __expf(a[n] - m);
    s += a[n];
  }
  const float inv = 1.f / s;
#pragma unroll
  for (int n = 0; n < NN; ++n) p[n * BB] = bf_round(a[n] * inv);
}

// ------------------------------------------------------------------ kS
// iterations 2-3: wave = (n, i-chunk of 16). s_acc += c * u; bf16 spart.
__global__ __launch_bounds__(256) void kS(const short* __restrict__ Wb,
                                          const short* __restrict__ xh,
                                          const short* __restrict__ xl,
                                          const unsigned short* __restrict__ ct,
                                          unsigned short* __restrict__ spart) {
  const int wv = threadIdx.x >> 6;
  const int lane = threadIdx.x & 63;
  const int bl = lane & 31;
  const int hi = lane >> 5;
  const int w = blockIdx.x * 4 + wv;
  const int n = w >> 7;
  const int ch = w & (NCHUNK - 1);

  f32x16 s0 = {};
  f32x16 s1 = {};

  const short* Wp = Wb + (((size_t)n * INP + (size_t)ch * ICH) * DD + bl) * KK + hi * 8;
  const short* xhp = xh + (size_t)ch * ICH * BB * KK + hi * 8;
  const short* xlp = xl + (size_t)ch * ICH * BB * KK + hi * 8;

#pragma unroll 2
  for (int ii = 0; ii < ICH; ++ii) {
    const short8 whi = *(const short8*)(Wp + (size_t)ii * (DD * KK));
    const short8 x0h = *(const short8*)(xhp + ii * (BB * KK) + bl * KK);
    const short8 x0l = *(const short8*)(xlp + ii * (BB * KK) + bl * KK);
    const short8 x1h = *(const short8*)(xhp + ii * (BB * KK) + (bl + 32) * KK);
    const short8 x1l = *(const short8*)(xlp + ii * (BB * KK) + (bl + 32) * KK);

    f32x16 u0 = {};
    u0 = __builtin_amdgcn_mfma_f32_32x32x16_bf16(whi, x0h, u0, 0, 0, 0);
    u0 = __builtin_amdgcn_mfma_f32_32x32x16_bf16(whi, x0l, u0, 0, 0, 0);
    f32x16 u1 = {};
    u1 = __builtin_amdgcn_mfma_f32_32x32x16_bf16(whi, x1h, u1, 0, 0, 0);
    u1 = __builtin_amdgcn_mfma_f32_32x32x16_bf16(whi, x1l, u1, 0, 0, 0);

    const int i = ch * ICH + ii;
    const float c0 = bf2f(ct[((size_t)i * NN + n) * BB + bl]);
    const float c1 = bf2f(ct[((size_t)i * NN + n) * BB + bl + 32]);
#pragma unroll
    for (int r = 0; r < 16; ++r) {
      s0[r] += c0 * u0[r];
      s1[r] += c1 * u1[r];
    }
  }

  const size_t off = ((size_t)ch * NN + n) * (DD * BB);
#pragma unroll
  for (int r = 0; r < 16; ++r) {
    const int d = (r & 3) + 8 * (r >> 2) + 4 * hi;
    spart[off + d * BB + bl] = bf_round(s0[r]);
    spart[off + d * BB + bl + 32] = bf_round(s1[r]);
  }
}

// ------------------------------------------------------------------ kR1h
// bf16 spart [nch][N][D][B] -> st fp32; uint loads (2 elems/thread).
__global__ void kR1h(const unsigned* __restrict__ spart, float2* __restrict__ st,
                     int nch) {
  const int t = blockIdx.x * 128 + threadIdx.x; // 32768 uint cells
  float s0 = 0.f, s1 = 0.f;
  for (int ch = 0; ch < nch; ++ch) {
    const unsigned u = spart[(size_t)ch * (NN * DD * BB / 2) + t];
    s0 += bf2f((unsigned short)(u & 0xFFFFu));
    s1 += bf2f((unsigned short)(u >> 16));
  }
  st[t] = make_float2(s0, s1);
}

// ------------------------------------------------------------------ kR2
// squash per (b,n); vsum = (first ? v : vsum + v); write out on last.
__global__ void kR2(const float* __restrict__ st, float* __restrict__ vsum,
                    float* __restrict__ out, int first, int last) {
  const int t = blockIdx.x * 64 + threadIdx.x; // B*N = 2048
  const int b = t & 63;
  const int n = t >> 6;
  float sd[DD];
  float s2 = 0.f;
#pragma unroll
  for (int d = 0; d < DD; ++d) {
    sd[d] = st[(n * DD + d) * BB + b];
    s2 += sd[d] * sd[d];
  }
  const float scale = s2 / (1.f + s2) / sqrtf(s2 + 1e-7f);
#pragma unroll
  for (int d = 0; d < DD; ++d) {
    const float v = scale * sd[d];
    const size_t idx = (size_t)(n * DD + d) * BB + b;
    vsum[idx] = first ? v : (vsum[idx] + v);
    if (last) out[((size_t)b * NN + n) * DD + d] = v;
  }
}

extern "C" void kernel_launch(void* const* d_in, const int* in_sizes, int n_in,
                              void* d_out, int out_size, void* d_ws,
                              size_t ws_size, hipStream_t stream) {
  const float* x = (const float*)d_in[0]; // [64,2048,16]
  const float* W = (const float*)d_in[1]; // [32,2048,32,16]
  float* out = (float*)d_out;             // [64,32,32]

  short* xh = (short*)d_ws;                            // [In][B][K] bf16 4.2 MB
  short* xl = xh + (size_t)INP * BB * KK;              // 4.2 MB
  short* Wbuf = xl + (size_t)INP * BB * KK;            // [N][In][D][K] bf16 67 MB
  unsigned short* ct = (unsigned short*)(Wbuf + (size_t)NN * INP * DD * KK); // 8.4 MB
  unsigned short* sparth = ct + (size_t)INP * NN * BB; // [256][N][D][B] bf16 33.5 MB
  float* st = (float*)(sparth + (size_t)S1NCH * NN * DD * BB); // 256 KB
  float* vsum = st + (size_t)NN * DD * BB;                      // 256 KB

  const int gS1 = (NN * S1NCH) / 4;          // 2048 blocks
  const int gW = (NN * NCHUNK) / 4;          // 1024 blocks
  const int gA = (NN * ANCH) / 4;            // 2048 blocks
  const int gT = (INP * BB) / 256;           // 512
  const int gSM = INP / 4;                   // 512
  const int gR1h = (NN * DD * BB / 2) / 128; // 256
  const int gR2 = (BB * NN) / 64;            // 32

  kT<<<gT, 256, 0, stream>>>(x, xh, xl);

  // iteration 1: c uniform; also converts W -> Wb; vsum = v (first)
  kS1c<<<gS1, 256, 0, stream>>>(W, xh, xl, Wbuf, sparth);
  kR1h<<<gR1h, 128, 0, stream>>>((const unsigned*)sparth, (float2*)st, S1NCH);
  kR2<<<gR2, 64, 0, stream>>>(st, vsum, out, 1, 0);
  // iterations 2..3 on bf16 W
  for (int it = 1; it < 3; ++it) {
    kA<<<gA, 256, 0, stream>>>(Wbuf, xh, vsum, ct);
    kSM<<<gSM, 256, 0, stream>>>(ct);
    kS<<<gW, 256, 0, stream>>>(Wbuf, xh, xl, ct, sparth);
    kR1h<<<gR1h, 128, 0, stream>>>((const unsigned*)sparth, (float2*)st, NCHUNK);
    kR2<<<gR2, 64, 0, stream>>>(st, vsum, out, 0, it == 2);
  }
}

// Round 13
// 174.464 us; speedup vs baseline: 1.7146x; 1.7146x over previous
//
#include <hip/hip_runtime.h>

// Capsule dynamic routing via MFMA, fused, u_hat never materialized.
//   x: [B=64, In=2048, K=16] fp32;  W: [N=32, In=2048, D=32, K=16] fp32
//   out v: [B=64, N=32, D=32] fp32
// Identities: b_t = u_hat . Vsum (logits linear in agreements); c_1 = 1/32.
// Per (n,i): u[d,b] = W[n,i] (32x16) @ x^T (16x64) via 2 b-tiles of
// mfma_f32_32x32x16_bf16.
// Structure (round-10 skeleton = best measured 176.6 us):
//   kT   : x -> xh/xl bf16 [In][B][K]
//   kS1c : iter-1 s (uniform c=1/32) + W->Wb convert; round 13: accumulate
//          from ROUNDED Wb with single MFMA per b-tile (iter-1 s only feeds
//          softmax-damped logits; same approx as kA, validated r8/r10).
//          Cuts split8 (~40 VALU/ii), xl loads, 4/6 MFMAs from the dep chain.
//   kA   : logits (single MFMA, Wb*xh), chunk=8
//   kSM  : softmax over n (in-place, bf16 ct)
//   kS   : weighted sum (Wb, x hi+lo — OUTPUT path keeps full accuracy)
//   kR1h/kR2 : wide reduction + squash
// NOTE (round-3): tiny-grid reduction kernels are latency disasters.
// NOTE (rounds 5/8/9): ALL fusion attempts lost 30-160 us. Streaming wins.
// NOTE (round-12): kS1c chunk 16->8 was a NULL on kS1c (76us both ways,
// occupancy-insensitive -> dep-chain-bound, not wave-starved); reverted.
// Round-12 total (299us) unexplained by code delta; container was swapped
// after r11 crash — treat as machine-degraded sample.

#define INP 2048
#define BB 64
#define KK 16
#define NN 32
#define DD 32
#define ICH 16
#define NCHUNK (INP / ICH)  // 128 (kS1c, kS, spart)
#define ACH 8
#define ANCH (INP / ACH)    // 256 (kA)

typedef __attribute__((ext_vector_type(8))) short short8;
typedef __attribute__((ext_vector_type(16))) float f32x16;

__device__ __forceinline__ short bf_trunc(float f) {
  return (short)(__builtin_bit_cast(unsigned, f) >> 16);
}
__device__ __forceinline__ unsigned short bf_round(float f) {
  unsigned u = __builtin_bit_cast(unsigned, f);
  return (unsigned short)((u + 0x8000u) >> 16);
}
__device__ __forceinline__ float bf2f(unsigned short u) {
  return __builtin_bit_cast(float, (unsigned)u << 16);
}

__device__ __forceinline__ void split8(float4 w0, float4 w1, short8& h, short8& l) {
  float f[8] = {w0.x, w0.y, w0.z, w0.w, w1.x, w1.y, w1.z, w1.w};
#pragma unroll
  for (int j = 0; j < 8; ++j) {
    unsigned u = __builtin_bit_cast(unsigned, f[j]);
    h[j] = (short)(u >> 16);
    float hf = __builtin_bit_cast(float, u & 0xFFFF0000u);
    l[j] = bf_trunc(f[j] - hf);
  }
}

// round-to-nearest bf16 of 8 fp32 (for the stored Wb)
__device__ __forceinline__ short8 round8(float4 w0, float4 w1) {
  float f[8] = {w0.x, w0.y, w0.z, w0.w, w1.x, w1.y, w1.z, w1.w};
  short8 r;
#pragma unroll
  for (int j = 0; j < 8; ++j) r[j] = (short)bf_round(f[j]);
  return r;
}

// ------------------------------------------------------------------ kT
// transpose x [B][In][K] fp32 -> xt_hi/xt_lo [In][B][K] bf16
__global__ __launch_bounds__(256) void kT(const float* __restrict__ x,
                                          short* __restrict__ xh,
                                          short* __restrict__ xl) {
  const int t = blockIdx.x * 256 + threadIdx.x; // In*B = 131072
  const int i = t >> 6, b = t & 63;
  const float4* xs = (const float4*)(x + ((size_t)b * INP + i) * KK);
  short8* dh = (short8*)(xh + ((size_t)i * BB + b) * KK);
  short8* dl = (short8*)(xl + ((size_t)i * BB + b) * KK);
#pragma unroll
  for (int h = 0; h < 2; ++h) {
    short8 hh, ll;
    split8(xs[h * 2], xs[h * 2 + 1], hh, ll);
    dh[h] = hh;
    dl[h] = ll;
  }
}

// ------------------------------------------------------------------ kS1c
// iteration 1 (c uniform = 1/32) + W->bf16 conversion. wave = (n, i-chunk of 16).
// Accumulates from ROUNDED Wb (single MFMA per b-tile); writes Wb + bf16 spart.
__global__ __launch_bounds__(256) void kS1c(const float* __restrict__ W,
                                            const short* __restrict__ xh,
                                            short* __restrict__ Wb,
                                            unsigned short* __restrict__ spart) {
  const int wv = threadIdx.x >> 6;
  const int lane = threadIdx.x & 63;
  const int bl = lane & 31;
  const int hi = lane >> 5;
  const int w = blockIdx.x * 4 + wv;
  const int n = w >> 7;           // / NCHUNK
  const int ch = w & (NCHUNK - 1);

  f32x16 s0 = {};
  f32x16 s1 = {};

  const size_t fragoff = (((size_t)n * INP + (size_t)ch * ICH) * DD + bl) * KK + hi * 8;
  const float* Wp = W + fragoff;
  short* Wbp = Wb + fragoff;
  const short* xhp = xh + (size_t)ch * ICH * BB * KK + hi * 8;

#pragma unroll 2
  for (int ii = 0; ii < ICH; ++ii) {
    float4 w0 = *(const float4*)(Wp + (size_t)ii * (DD * KK));
    float4 w1 = *(const float4*)(Wp + (size_t)ii * (DD * KK) + 4);
    const short8 wb = round8(w0, w1);
    *(short8*)(Wbp + (size_t)ii * (DD * KK)) = wb; // store Wb
    const short8 x0h = *(const short8*)(xhp + ii * (BB * KK) + bl * KK);
    const short8 x1h = *(const short8*)(xhp + ii * (BB * KK) + (bl + 32) * KK);
    s0 = __builtin_amdgcn_mfma_f32_32x32x16_bf16(wb, x0h, s0, 0, 0, 0);
    s1 = __builtin_amdgcn_mfma_f32_32x32x16_bf16(wb, x1h, s1, 0, 0, 0);
  }

  const size_t off = ((size_t)ch * NN + n) * (DD * BB);
#pragma unroll
  for (int r = 0; r < 16; ++r) {
    const int d = (r & 3) + 8 * (r >> 2) + 4 * hi;
    spart[off + d * BB + bl] = bf_round(0.03125f * s0[r]);
    spart[off + d * BB + bl + 32] = bf_round(0.03125f * s1[r]);
  }
}

// ------------------------------------------------------------------ kA
// wave = (n, i-chunk of 8). a[b,n,i] = sum_d u[d,b]*vsum[b,n,d] -> ct bf16.
// single-MFMA u (x hi only): logit error is softmax-damped + i-averaged.
__global__ __launch_bounds__(256) void kA(const short* __restrict__ Wb,
                                          const short* __restrict__ xh,
                                          const float* __restrict__ vsum,
                                          unsigned short* __restrict__ ct) {
  const int wv = threadIdx.x >> 6;
  const int lane = threadIdx.x & 63;
  const int bl = lane & 31;
  const int hi = lane >> 5;
  const int w = blockIdx.x * 4 + wv;
  const int n = w >> 8;           // / ANCH
  const int ch = w & (ANCH - 1);

  float vr0[16], vr1[16];
#pragma unroll
  for (int r = 0; r < 16; ++r) {
    const int d = (r & 3) + 8 * (r >> 2) + 4 * hi;
    vr0[r] = vsum[((size_t)n * DD + d) * BB + bl];
    vr1[r] = vsum[((size_t)n * DD + d) * BB + bl + 32];
  }

  const short* Wp = Wb + (((size_t)n * INP + (size_t)ch * ACH) * DD + bl) * KK + hi * 8;
  const short* xhp = xh + (size_t)ch * ACH * BB * KK + hi * 8;

#pragma unroll 2
  for (int ii = 0; ii < ACH; ++ii) {
    const short8 whi = *(const short8*)(Wp + (size_t)ii * (DD * KK));
    const short8 x0h = *(const short8*)(xhp + ii * (BB * KK) + bl * KK);
    const short8 x1h = *(const short8*)(xhp + ii * (BB * KK) + (bl + 32) * KK);

    f32x16 u0 = {};
    u0 = __builtin_amdgcn_mfma_f32_32x32x16_bf16(whi, x0h, u0, 0, 0, 0);
    f32x16 u1 = {};
    u1 = __builtin_amdgcn_mfma_f32_32x32x16_bf16(whi, x1h, u1, 0, 0, 0);

    float p0 = 0.f, p1 = 0.f;
#pragma unroll
    for (int r = 0; r < 16; ++r) {
      p0 += u0[r] * vr0[r];
      p1 += u1[r] * vr1[r];
    }
    p0 += __shfl_xor(p0, 32, 64);
    p1 += __shfl_xor(p1, 32, 64);
    const int i = ch * ACH + ii;
    ct[((size_t)i * NN + n) * BB + lane] = bf_round((lane < 32) ? p0 : p1);
  }
}

// ------------------------------------------------------------------ kSM
// in-place softmax over n for each (i, b); wave per i, lane = b. bf16 ct.
__global__ __launch_bounds__(256) void kSM(unsigned short* __restrict__ ct) {
  const int wv = threadIdx.x >> 6;
  const int lane = threadIdx.x & 63;
  const int i = blockIdx.x * 4 + wv;
  unsigned short* p = ct + (size_t)i * NN * BB + lane;
  float a[NN];
  float m = -1e30f;
#pragma unroll
  for (int n = 0; n < NN; ++n) {
    a[n] = bf2f(p[n * BB]);
    m = fmaxf(m, a[n]);
  }
  float s = 0.f;
#pragma unroll
  for (int n = 0; n < NN; ++n) {
    a[n] = __expf(a[n] - m);
    s += a[n];
  }
  const float inv = 1.f / s;
#pragma unroll
  for (int n = 0; n < NN; ++n) p[n * BB] = bf_round(a[n] * inv);
}

// ------------------------------------------------------------------ kS
// iterations 2-3: wave = (n, i-chunk of 16). s_acc += c * u; bf16 spart.
// OUTPUT path: keeps x hi+lo for full input accuracy.
__global__ __launch_bounds__(256) void kS(const short* __restrict__ Wb,
                                          const short* __restrict__ xh,
                                          const short* __restrict__ xl,
                                          const unsigned short* __restrict__ ct,
                                          unsigned short* __restrict__ spart) {
  const int wv = threadIdx.x >> 6;
  const int lane = threadIdx.x & 63;
  const int bl = lane & 31;
  const int hi = lane >> 5;
  const int w = blockIdx.x * 4 + wv;
  const int n = w >> 7;
  const int ch = w & (NCHUNK - 1);

  f32x16 s0 = {};
  f32x16 s1 = {};

  const short* Wp = Wb + (((size_t)n * INP + (size_t)ch * ICH) * DD + bl) * KK + hi * 8;
  const short* xhp = xh + (size_t)ch * ICH * BB * KK + hi * 8;
  const short* xlp = xl + (size_t)ch * ICH * BB * KK + hi * 8;

#pragma unroll 2
  for (int ii = 0; ii < ICH; ++ii) {
    const short8 whi = *(const short8*)(Wp + (size_t)ii * (DD * KK));
    const short8 x0h = *(const short8*)(xhp + ii * (BB * KK) + bl * KK);
    const short8 x0l = *(const short8*)(xlp + ii * (BB * KK) + bl * KK);
    const short8 x1h = *(const short8*)(xhp + ii * (BB * KK) + (bl + 32) * KK);
    const short8 x1l = *(const short8*)(xlp + ii * (BB * KK) + (bl + 32) * KK);

    f32x16 u0 = {};
    u0 = __builtin_amdgcn_mfma_f32_32x32x16_bf16(whi, x0h, u0, 0, 0, 0);
    u0 = __builtin_amdgcn_mfma_f32_32x32x16_bf16(whi, x0l, u0, 0, 0, 0);
    f32x16 u1 = {};
    u1 = __builtin_amdgcn_mfma_f32_32x32x16_bf16(whi, x1h, u1, 0, 0, 0);
    u1 = __builtin_amdgcn_mfma_f32_32x32x16_bf16(whi, x1l, u1, 0, 0, 0);

    const int i = ch * ICH + ii;
    const float c0 = bf2f(ct[((size_t)i * NN + n) * BB + bl]);
    const float c1 = bf2f(ct[((size_t)i * NN + n) * BB + bl + 32]);
#pragma unroll
    for (int r = 0; r < 16; ++r) {
      s0[r] += c0 * u0[r];
      s1[r] += c1 * u1[r];
    }
  }

  const size_t off = ((size_t)ch * NN + n) * (DD * BB);
#pragma unroll
  for (int r = 0; r < 16; ++r) {
    const int d = (r & 3) + 8 * (r >> 2) + 4 * hi;
    spart[off + d * BB + bl] = bf_round(s0[r]);
    spart[off + d * BB + bl + 32] = bf_round(s1[r]);
  }
}

// ------------------------------------------------------------------ kR1h
// bf16 spart [128][N][D][B] -> st fp32; uint loads (2 elems/thread).
__global__ void kR1h(const unsigned* __restrict__ spart, float2* __restrict__ st) {
  const int t = blockIdx.x * 128 + threadIdx.x; // 32768 uint cells
  float s0 = 0.f, s1 = 0.f;
  for (int ch = 0; ch < NCHUNK; ++ch) {
    const unsigned u = spart[(size_t)ch * (NN * DD * BB / 2) + t];
    s0 += bf2f((unsigned short)(u & 0xFFFFu));
    s1 += bf2f((unsigned short)(u >> 16));
  }
  st[t] = make_float2(s0, s1);
}

// ------------------------------------------------------------------ kR2
// squash per (b,n); vsum = (first ? v : vsum + v); write out on last.
__global__ void kR2(const float* __restrict__ st, float* __restrict__ vsum,
                    float* __restrict__ out, int first, int last) {
  const int t = blockIdx.x * 64 + threadIdx.x; // B*N = 2048
  const int b = t & 63;
  const int n = t >> 6;
  float sd[DD];
  float s2 = 0.f;
#pragma unroll
  for (int d = 0; d < DD; ++d) {
    sd[d] = st[(n * DD + d) * BB + b];
    s2 += sd[d] * sd[d];
  }
  const float scale = s2 / (1.f + s2) / sqrtf(s2 + 1e-7f);
#pragma unroll
  for (int d = 0; d < DD; ++d) {
    const float v = scale * sd[d];
    const size_t idx = (size_t)(n * DD + d) * BB + b;
    vsum[idx] = first ? v : (vsum[idx] + v);
    if (last) out[((size_t)b * NN + n) * DD + d] = v;
  }
}

extern "C" void kernel_launch(void* const* d_in, const int* in_sizes, int n_in,
                              void* d_out, int out_size, void* d_ws,
                              size_t ws_size, hipStream_t stream) {
  const float* x = (const float*)d_in[0]; // [64,2048,16]
  const float* W = (const float*)d_in[1]; // [32,2048,32,16]
  float* out = (float*)d_out;             // [64,32,32]

  short* xh = (short*)d_ws;                            // [In][B][K] bf16 4.2 MB
  short* xl = xh + (size_t)INP * BB * KK;              // 4.2 MB
  short* Wbuf = xl + (size_t)INP * BB * KK;            // [N][In][D][K] bf16 67 MB
  unsigned short* ct = (unsigned short*)(Wbuf + (size_t)NN * INP * DD * KK); // 8.4 MB
  unsigned short* sparth = ct + (size_t)INP * NN * BB; // [128][N][D][B] bf16 16.8 MB
  float* st = (float*)(sparth + (size_t)NCHUNK * NN * DD * BB); // 256 KB
  float* vsum = st + (size_t)NN * DD * BB;                       // 256 KB

  const int gW = (NN * NCHUNK) / 4;          // 1024 blocks, 4 waves each
  const int gA = (NN * ANCH) / 4;            // 2048 blocks
  const int gT = (INP * BB) / 256;           // 512
  const int gSM = INP / 4;                   // 512
  const int gR1h = (NN * DD * BB / 2) / 128; // 256
  const int gR2 = (BB * NN) / 64;            // 32

  kT<<<gT, 256, 0, stream>>>(x, xh, xl);

  // iteration 1: c uniform; also converts W -> Wb; vsum = v (first)
  kS1c<<<gW, 256, 0, stream>>>(W, xh, Wbuf, sparth);
  kR1h<<<gR1h, 128, 0, stream>>>((const unsigned*)sparth, (float2*)st);
  kR2<<<gR2, 64, 0, stream>>>(st, vsum, out, 1, 0);
  // iterations 2..3 on bf16 W
  for (int it = 1; it < 3; ++it) {
    kA<<<gA, 256, 0, stream>>>(Wbuf, xh, vsum, ct);
    kSM<<<gSM, 256, 0, stream>>>(ct);
    kS<<<gW, 256, 0, stream>>>(Wbuf, xh, xl, ct, sparth);
    kR1h<<<gR1h, 128, 0, stream>>>((const unsigned*)sparth, (float2*)st);
    kR2<<<gR2, 64, 0, stream>>>(st, vsum, out, 0, it == 2);
  }
}

// Round 15
// 162.874 us; speedup vs baseline: 1.8367x; 1.0712x over previous
//
#include <hip/hip_runtime.h>

// Capsule dynamic routing via MFMA, fused, u_hat never materialized.
//   x: [B=64, In=2048, K=16] fp32;  W: [N=32, In=2048, D=32, K=16] fp32
//   out v: [B=64, N=32, D=32] fp32
// Identities: b_t = u_hat . Vsum (logits linear in agreements); c_1 = 1/32.
// Per (n,i): u[d,b] = W[n,i] (32x16) @ x^T (16x64) via 2 b-tiles of
// mfma_f32_32x32x16_bf16.
// Structure (round-13 best = 174.5 us):
//   kT   : x -> xh/xl bf16 [In][B][K]
//   kS1c : iter-1 s (uniform c=1/32) + W->Wb convert (rounded-Wb accum)
//   kA   : logits (single MFMA, Wb*xh), chunk=8
//   kSM  : softmax over n (in-place, bf16 ct)
//   kS   : weighted sum (Wb, x hi+lo — output path keeps full x accuracy)
//   kR1h/kR2 : wide reduction + squash
// Round 14/15: 4-wave block partial-reduce of spart in kS1c/kS via padded LDS
// ([4][64][33], conflict-free) -> spart 128->32 chunks (16.8->4.2 MB),
// kR1h serial walk 128->32. Within-block tail exchange only (NOT the failed
// cross-pass fusion: no W re-read across the barrier).
// NOTE (round-3): tiny-grid / long-serial-chain reductions are latency traps.
// NOTE (rounds 5/8/9): cross-pass fusion lost 30-160 us every time.
// NOTE (round-12): kS1c is dep-chain-bound, not wave-starved (chunk split null).
// NOTE (round-14): bench infra failure (UnresponsiveContainer); resubmitted.

#define INP 2048
#define BB 64
#define KK 16
#define NN 32
#define DD 32
#define ICH 16
#define NCHUNK (INP / ICH)  // 128 i-chunks
#define NGRP (NCHUNK / 4)   // 32 spart chunks (4-wave block reduce)
#define ACH 8
#define ANCH (INP / ACH)    // 256 (kA)

typedef __attribute__((ext_vector_type(8))) short short8;
typedef __attribute__((ext_vector_type(16))) float f32x16;

__device__ __forceinline__ short bf_trunc(float f) {
  return (short)(__builtin_bit_cast(unsigned, f) >> 16);
}
__device__ __forceinline__ unsigned short bf_round(float f) {
  unsigned u = __builtin_bit_cast(unsigned, f);
  return (unsigned short)((u + 0x8000u) >> 16);
}
__device__ __forceinline__ float bf2f(unsigned short u) {
  return __builtin_bit_cast(float, (unsigned)u << 16);
}

__device__ __forceinline__ void split8(float4 w0, float4 w1, short8& h, short8& l) {
  float f[8] = {w0.x, w0.y, w0.z, w0.w, w1.x, w1.y, w1.z, w1.w};
#pragma unroll
  for (int j = 0; j < 8; ++j) {
    unsigned u = __builtin_bit_cast(unsigned, f[j]);
    h[j] = (short)(u >> 16);
    float hf = __builtin_bit_cast(float, u & 0xFFFF0000u);
    l[j] = bf_trunc(f[j] - hf);
  }
}

// round-to-nearest bf16 of 8 fp32 (for the stored Wb)
__device__ __forceinline__ short8 round8(float4 w0, float4 w1) {
  float f[8] = {w0.x, w0.y, w0.z, w0.w, w1.x, w1.y, w1.z, w1.w};
  short8 r;
#pragma unroll
  for (int j = 0; j < 8; ++j) r[j] = (short)bf_round(f[j]);
  return r;
}

// ------------------------------------------------------------------ kT
// transpose x [B][In][K] fp32 -> xt_hi/xt_lo [In][B][K] bf16
__global__ __launch_bounds__(256) void kT(const float* __restrict__ x,
                                          short* __restrict__ xh,
                                          short* __restrict__ xl) {
  const int t = blockIdx.x * 256 + threadIdx.x; // In*B = 131072
  const int i = t >> 6, b = t & 63;
  const float4* xs = (const float4*)(x + ((size_t)b * INP + i) * KK);
  short8* dh = (short8*)(xh + ((size_t)i * BB + b) * KK);
  short8* dl = (short8*)(xl + ((size_t)i * BB + b) * KK);
#pragma unroll
  for (int h = 0; h < 2; ++h) {
    short8 hh, ll;
    split8(xs[h * 2], xs[h * 2 + 1], hh, ll);
    dh[h] = hh;
    dl[h] = ll;
  }
}

// cross-wave (4-wave) reduce of s0/s1 through padded LDS, then write spart.
// lds[4][64][33]: bank = (lane + r) & 31 -> conflict-free. Each wave writes
// 8 of the 32 (r) values of the block-sum.
__device__ __forceinline__ void block_reduce_store(
    float lds[4][64][33], const f32x16& s0, const f32x16& s1, int wv, int lane,
    int bl, int hi, unsigned short* __restrict__ spart, size_t off, float scale) {
#pragma unroll
  for (int r = 0; r < 16; ++r) {
    lds[wv][lane][r] = s0[r];
    lds[wv][lane][r + 16] = s1[r];
  }
  __syncthreads();
#pragma unroll
  for (int j = 0; j < 8; ++j) {
    const int rp = wv * 8 + j;
    const float sum = lds[0][lane][rp] + lds[1][lane][rp] +
                      lds[2][lane][rp] + lds[3][lane][rp];
    const int rr = rp & 15;
    const int d = (rr & 3) + 8 * (rr >> 2) + 4 * hi;
    const int b = bl + (rp >> 4) * 32;
    spart[off + d * BB + b] = bf_round(scale * sum);
  }
}

// ------------------------------------------------------------------ kS1c
// iteration 1 (c uniform = 1/32) + W->bf16 conversion. Block = (n, 4 adjacent
// i-chunks of 16); accumulates from ROUNDED Wb (single MFMA per b-tile);
// 4-wave block reduce -> spart[32 grp].
__global__ __launch_bounds__(256) void kS1c(const float* __restrict__ W,
                                            const short* __restrict__ xh,
                                            short* __restrict__ Wb,
                                            unsigned short* __restrict__ spart) {
  __shared__ float lds[4][64][33];
  const int wv = threadIdx.x >> 6;
  const int lane = threadIdx.x & 63;
  const int bl = lane & 31;
  const int hi = lane >> 5;
  const int n = blockIdx.x >> 5;       // 32 n
  const int chg = blockIdx.x & 31;     // 32 chunk-groups
  const int ch = chg * 4 + wv;         // this wave's i-chunk

  f32x16 s0 = {};
  f32x16 s1 = {};

  const size_t fragoff = (((size_t)n * INP + (size_t)ch * ICH) * DD + bl) * KK + hi * 8;
  const float* Wp = W + fragoff;
  short* Wbp = Wb + fragoff;
  const short* xhp = xh + (size_t)ch * ICH * BB * KK + hi * 8;

#pragma unroll 2
  for (int ii = 0; ii < ICH; ++ii) {
    float4 w0 = *(const float4*)(Wp + (size_t)ii * (DD * KK));
    float4 w1 = *(const float4*)(Wp + (size_t)ii * (DD * KK) + 4);
    const short8 wb = round8(w0, w1);
    *(short8*)(Wbp + (size_t)ii * (DD * KK)) = wb; // store Wb
    const short8 x0h = *(const short8*)(xhp + ii * (BB * KK) + bl * KK);
    const short8 x1h = *(const short8*)(xhp + ii * (BB * KK) + (bl + 32) * KK);
    s0 = __builtin_amdgcn_mfma_f32_32x32x16_bf16(wb, x0h, s0, 0, 0, 0);
    s1 = __builtin_amdgcn_mfma_f32_32x32x16_bf16(wb, x1h, s1, 0, 0, 0);
  }

  const size_t off = ((size_t)chg * NN + n) * (DD * BB);
  block_reduce_store(lds, s0, s1, wv, lane, bl, hi, spart, off, 0.03125f);
}

// ------------------------------------------------------------------ kA
// wave = (n, i-chunk of 8). a[b,n,i] = sum_d u[d,b]*vsum[b,n,d] -> ct bf16.
// single-MFMA u (x hi only): logit error is softmax-damped + i-averaged.
__global__ __launch_bounds__(256) void kA(const short* __restrict__ Wb,
                                          const short* __restrict__ xh,
                                          const float* __restrict__ vsum,
                                          unsigned short* __restrict__ ct) {
  const int wv = threadIdx.x >> 6;
  const int lane = threadIdx.x & 63;
  const int bl = lane & 31;
  const int hi = lane >> 5;
  const int w = blockIdx.x * 4 + wv;
  const int n = w >> 8;           // / ANCH
  const int ch = w & (ANCH - 1);

  float vr0[16], vr1[16];
#pragma unroll
  for (int r = 0; r < 16; ++r) {
    const int d = (r & 3) + 8 * (r >> 2) + 4 * hi;
    vr0[r] = vsum[((size_t)n * DD + d) * BB + bl];
    vr1[r] = vsum[((size_t)n * DD + d) * BB + bl + 32];
  }

  const short* Wp = Wb + (((size_t)n * INP + (size_t)ch * ACH) * DD + bl) * KK + hi * 8;
  const short* xhp = xh + (size_t)ch * ACH * BB * KK + hi * 8;

#pragma unroll 2
  for (int ii = 0; ii < ACH; ++ii) {
    const short8 whi = *(const short8*)(Wp + (size_t)ii * (DD * KK));
    const short8 x0h = *(const short8*)(xhp + ii * (BB * KK) + bl * KK);
    const short8 x1h = *(const short8*)(xhp + ii * (BB * KK) + (bl + 32) * KK);

    f32x16 u0 = {};
    u0 = __builtin_amdgcn_mfma_f32_32x32x16_bf16(whi, x0h, u0, 0, 0, 0);
    f32x16 u1 = {};
    u1 = __builtin_amdgcn_mfma_f32_32x32x16_bf16(whi, x1h, u1, 0, 0, 0);

    float p0 = 0.f, p1 = 0.f;
#pragma unroll
    for (int r = 0; r < 16; ++r) {
      p0 += u0[r] * vr0[r];
      p1 += u1[r] * vr1[r];
    }
    p0 += __shfl_xor(p0, 32, 64);
    p1 += __shfl_xor(p1, 32, 64);
    const int i = ch * ACH + ii;
    ct[((size_t)i * NN + n) * BB + lane] = bf_round((lane < 32) ? p0 : p1);
  }
}

// ------------------------------------------------------------------ kSM
// in-place softmax over n for each (i, b); wave per i, lane = b. bf16 ct.
__global__ __launch_bounds__(256) void kSM(unsigned short* __restrict__ ct) {
  const int wv = threadIdx.x >> 6;
  const int lane = threadIdx.x & 63;
  const int i = blockIdx.x * 4 + wv;
  unsigned short* p = ct + (size_t)i * NN * BB + lane;
  float a[NN];
  float m = -1e30f;
#pragma unroll
  for (int n = 0; n < NN; ++n) {
    a[n] = bf2f(p[n * BB]);
    m = fmaxf(m, a[n]);
  }
  float s = 0.f;
#pragma unroll
  for (int n = 0; n < NN; ++n) {
    a[n] = __expf(a[n] - m);
    s += a[n];
  }
  const float inv = 1.f / s;
#pragma unroll
  for (int n = 0; n < NN; ++n) p[n * BB] = bf_round(a[n] * inv);
}

// ------------------------------------------------------------------ kS
// iterations 2-3: block = (n, 4 adjacent i-chunks of 16). s_acc += c * u;
// 4-wave block reduce -> spart[32 grp]. Output path keeps x hi+lo.
__global__ __launch_bounds__(256) void kS(const short* __restrict__ Wb,
                                          const short* __restrict__ xh,
                                          const short* __restrict__ xl,
                                          const unsigned short* __restrict__ ct,
                                          unsigned short* __restrict__ spart) {
  __shared__ float lds[4][64][33];
  const int wv = threadIdx.x >> 6;
  const int lane = threadIdx.x & 63;
  const int bl = lane & 31;
  const int hi = lane >> 5;
  const int n = blockIdx.x >> 5;
  const int chg = blockIdx.x & 31;
  const int ch = chg * 4 + wv;

  f32x16 s0 = {};
  f32x16 s1 = {};

  const short* Wp = Wb + (((size_t)n * INP + (size_t)ch * ICH) * DD + bl) * KK + hi * 8;
  const short* xhp = xh + (size_t)ch * ICH * BB * KK + hi * 8;
  const short* xlp = xl + (size_t)ch * ICH * BB * KK + hi * 8;

#pragma unroll 2
  for (int ii = 0; ii < ICH; ++ii) {
    const short8 whi = *(const short8*)(Wp + (size_t)ii * (DD * KK));
    const short8 x0h = *(const short8*)(xhp + ii * (BB * KK) + bl * KK);
    const short8 x0l = *(const short8*)(xlp + ii * (BB * KK) + bl * KK);
    const short8 x1h = *(const short8*)(xhp + ii * (BB * KK) + (bl + 32) * KK);
    const short8 x1l = *(const short8*)(xlp + ii * (BB * KK) + (bl + 32) * KK);

    f32x16 u0 = {};
    u0 = __builtin_amdgcn_mfma_f32_32x32x16_bf16(whi, x0h, u0, 0, 0, 0);
    u0 = __builtin_amdgcn_mfma_f32_32x32x16_bf16(whi, x0l, u0, 0, 0, 0);
    f32x16 u1 = {};
    u1 = __builtin_amdgcn_mfma_f32_32x32x16_bf16(whi, x1h, u1, 0, 0, 0);
    u1 = __builtin_amdgcn_mfma_f32_32x32x16_bf16(whi, x1l, u1, 0, 0, 0);

    const int i = ch * ICH + ii;
    const float c0 = bf2f(ct[((size_t)i * NN + n) * BB + bl]);
    const float c1 = bf2f(ct[((size_t)i * NN + n) * BB + bl + 32]);
#pragma unroll
    for (int r = 0; r < 16; ++r) {
      s0[r] += c0 * u0[r];
      s1[r] += c1 * u1[r];
    }
  }

  const size_t off = ((size_t)chg * NN + n) * (DD * BB);
  block_reduce_store(lds, s0, s1, wv, lane, bl, hi, spart, off, 1.0f);
}

// ------------------------------------------------------------------ kR1h
// bf16 spart [32][N][D][B] -> st fp32; uint loads (2 elems/thread).
__global__ void kR1h(const unsigned* __restrict__ spart, float2* __restrict__ st) {
  const int t = blockIdx.x * 128 + threadIdx.x; // 32768 uint cells
  float s0 = 0.f, s1 = 0.f;
  for (int g = 0; g < NGRP; ++g) {
    const unsigned u = spart[(size_t)g * (NN * DD * BB / 2) + t];
    s0 += bf2f((unsigned short)(u & 0xFFFFu));
    s1 += bf2f((unsigned short)(u >> 16));
  }
  st[t] = make_float2(s0, s1);
}

// ------------------------------------------------------------------ kR2
// squash per (b,n); vsum = (first ? v : vsum + v); write out on last.
__global__ void kR2(const float* __restrict__ st, float* __restrict__ vsum,
                    float* __restrict__ out, int first, int last) {
  const int t = blockIdx.x * 64 + threadIdx.x; // B*N = 2048
  const int b = t & 63;
  const int n = t >> 6;
  float sd[DD];
  float s2 = 0.f;
#pragma unroll
  for (int d = 0; d < DD; ++d) {
    sd[d] = st[(n * DD + d) * BB + b];
    s2 += sd[d] * sd[d];
  }
  const float scale = s2 / (1.f + s2) / sqrtf(s2 + 1e-7f);
#pragma unroll
  for (int d = 0; d < DD; ++d) {
    const float v = scale * sd[d];
    const size_t idx = (size_t)(n * DD + d) * BB + b;
    vsum[idx] = first ? v : (vsum[idx] + v);
    if (last) out[((size_t)b * NN + n) * DD + d] = v;
  }
}

extern "C" void kernel_launch(void* const* d_in, const int* in_sizes, int n_in,
                              void* d_out, int out_size, void* d_ws,
                              size_t ws_size, hipStream_t stream) {
  const float* x = (const float*)d_in[0]; // [64,2048,16]
  const float* W = (const float*)d_in[1]; // [32,2048,32,16]
  float* out = (float*)d_out;             // [64,32,32]

  short* xh = (short*)d_ws;                            // [In][B][K] bf16 4.2 MB
  short* xl = xh + (size_t)INP * BB * KK;              // 4.2 MB
  short* Wbuf = xl + (size_t)INP * BB * KK;            // [N][In][D][K] bf16 67 MB
  unsigned short* ct = (unsigned short*)(Wbuf + (size_t)NN * INP * DD * KK); // 8.4 MB
  unsigned short* sparth = ct + (size_t)INP * NN * BB; // [32][N][D][B] bf16 4.2 MB
  float* st = (float*)(sparth + (size_t)NGRP * NN * DD * BB); // 256 KB
  float* vsum = st + (size_t)NN * DD * BB;                     // 256 KB

  const int gW = NN * NGRP;                  // 1024 blocks (n x chunk-group)
  const int gA = (NN * ANCH) / 4;            // 2048 blocks
  const int gT = (INP * BB) / 256;           // 512
  const int gSM = INP / 4;                   // 512
  const int gR1h = (NN * DD * BB / 2) / 128; // 256
  const int gR2 = (BB * NN) / 64;            // 32

  kT<<<gT, 256, 0, stream>>>(x, xh, xl);

  // iteration 1: c uniform; also converts W -> Wb; vsum = v (first)
  kS1c<<<gW, 256, 0, stream>>>(W, xh, Wbuf, sparth);
  kR1h<<<gR1h, 128, 0, stream>>>((const unsigned*)sparth, (float2*)st);
  kR2<<<gR2, 64, 0, stream>>>(st, vsum, out, 1, 0);
  // iterations 2..3 on bf16 W
  for (int it = 1; it < 3; ++it) {
    kA<<<gA, 256, 0, stream>>>(Wbuf, xh, vsum, ct);
    kSM<<<gSM, 256, 0, stream>>>(ct);
    kS<<<gW, 256, 0, stream>>>(Wbuf, xh, xl, ct, sparth);
    kR1h<<<gR1h, 128, 0, stream>>>((const unsigned*)sparth, (float2*)st);
    kR2<<<gR2, 64, 0, stream>>>(st, vsum, out, 0, it == 2);
  }
}